// Round 3
// baseline (379.260 us; speedup 1.0000x reference)
//
#include <hip/hip_runtime.h>
#include <stdint.h>

#define D_DIM 128
#define NROW 8192
#define MROW 8192
#define TILE 128
#define OUT_LD 8192

typedef __bf16 bf16x8 __attribute__((ext_vector_type(8)));
typedef float f32x4 __attribute__((ext_vector_type(4)));

// Native bf16 converts (gfx950 v_cvt_pk_bf16_f32) — 8 f32 -> one A/B fragment.
__device__ __forceinline__ bf16x8 cvt8(float4 u, float4 v) {
    bf16x8 r;
    r[0] = (__bf16)u.x; r[1] = (__bf16)u.y; r[2] = (__bf16)u.z; r[3] = (__bf16)u.w;
    r[4] = (__bf16)v.x; r[5] = (__bf16)v.y; r[6] = (__bf16)v.z; r[7] = (__bf16)v.w;
    return r;
}

// Exact f32 row norms: one wave per row, X rows then Y rows, into d_ws.
__global__ __launch_bounds__(256) void rbf_norms(const float* __restrict__ X,
                                                 const float* __restrict__ Y,
                                                 float* __restrict__ nrm) {
    const int t = threadIdx.x;
    const int w = t >> 6, lane = t & 63;
    const int rid = blockIdx.x * 4 + w;
    const float* src = (rid < NROW) ? (X + (size_t)rid * D_DIM)
                                    : (Y + (size_t)(rid - NROW) * D_DIM);
    float2 v = *(const float2*)(src + 2 * lane);
    float s = v.x * v.x + v.y * v.y;
    #pragma unroll
    for (int off = 32; off > 0; off >>= 1) s += __shfl_xor(s, off, 64);
    if (lane == 0) nrm[rid] = s;
}

// Zero-LDS, zero-barrier: each wave owns a 64x64 output tile and loads its
// MFMA fragments straight from global (inputs are 8 MB, L1/L2-hot).
// Fragment layout (16x16x32 bf16): operand row = lane&15, k = (lane>>4)*8 + j,
// i.e. each lane reads 8 consecutive f32 = two float4 from one input row.
// Operands swapped (A=Y frag, B=X frag) -> D: col(n)=l16 -> out row,
// row(m)=quad*4+r -> out col, so the 4 acc regs are 4 consecutive out columns
// -> direct dwordx4 stores.
__global__ __launch_bounds__(256, 4) void rbf_main(const float* __restrict__ X,
                                                   const float* __restrict__ Y,
                                                   const float* __restrict__ sigma,
                                                   const float* __restrict__ nrm,
                                                   float* __restrict__ out) {
    const int t = threadIdx.x;
    const int w = t >> 6, ln = t & 63;
    const int quad = ln >> 4, l16 = ln & 15;
    const int rw = blockIdx.y * TILE + (w >> 1) * 64;  // out-row base (X rows) for wave
    const int cw = blockIdx.x * TILE + (w & 1) * 64;   // out-col base (Y rows) for wave

    const float* xr = X + (size_t)(rw + l16) * D_DIM + quad * 8;
    const float* yr = Y + (size_t)(cw + l16) * D_DIM + quad * 8;

    f32x4 acc[4][4] = {};   // [ti = out-row 16-frag][tj = out-col 16-frag]
    #pragma unroll
    for (int ks = 0; ks < 4; ++ks) {
        bf16x8 a[4], b[4];
        #pragma unroll
        for (int tj = 0; tj < 4; ++tj) {
            const float* p = yr + tj * (16 * D_DIM) + ks * 32;
            a[tj] = cvt8(*(const float4*)p, *(const float4*)(p + 4));
        }
        #pragma unroll
        for (int ti = 0; ti < 4; ++ti) {
            const float* p = xr + ti * (16 * D_DIM) + ks * 32;
            b[ti] = cvt8(*(const float4*)p, *(const float4*)(p + 4));
        }
        #pragma unroll
        for (int ti = 0; ti < 4; ++ti)
            #pragma unroll
            for (int tj = 0; tj < 4; ++tj)
                acc[ti][tj] = __builtin_amdgcn_mfma_f32_16x16x32_bf16(a[tj], b[ti], acc[ti][tj], 0, 0, 0);
    }

    const float s2 = sigma[0] * sigma[0] + 1e-9f;
    const float cexp = -1.4426950408889634f / s2;   // exp(-d/s2) = exp2(d * cexp)

    float x2r[4];
    #pragma unroll
    for (int ti = 0; ti < 4; ++ti) x2r[ti] = nrm[rw + ti * 16 + l16];

    #pragma unroll
    for (int tj = 0; tj < 4; ++tj) {
        f32x4 y2v = *(const f32x4*)(nrm + NROW + cw + tj * 16 + quad * 4);
        size_t gcol = (size_t)(cw + tj * 16 + quad * 4);
        #pragma unroll
        for (int ti = 0; ti < 4; ++ti) {
            f32x4 v;
            #pragma unroll
            for (int r = 0; r < 4; ++r) {
                float d = x2r[ti] + y2v[r] - 2.0f * acc[ti][tj][r];
                v[r] = __builtin_amdgcn_exp2f(d * cexp);
            }
            size_t grow = (size_t)(rw + ti * 16 + l16);
            __builtin_nontemporal_store(v, (f32x4*)(out + grow * OUT_LD + gcol));
        }
    }
}

extern "C" void kernel_launch(void* const* d_in, const int* in_sizes, int n_in,
                              void* d_out, int out_size, void* d_ws, size_t ws_size,
                              hipStream_t stream) {
    const float* X = (const float*)d_in[0];
    const float* Y = (const float*)d_in[1];
    const float* sigma = (const float*)d_in[2];
    float* nrm = (float*)d_ws;          // 16384 f32 = 64 KB scratch
    float* out = (float*)d_out;

    rbf_norms<<<(NROW + MROW) / 4, 256, 0, stream>>>(X, Y, nrm);
    rbf_main<<<dim3(MROW / TILE, NROW / TILE), 256, 0, stream>>>(X, Y, sigma, nrm, out);
}

// Round 4
// 314.843 us; speedup vs baseline: 1.2046x; 1.2046x over previous
//
#include <hip/hip_runtime.h>
#include <stdint.h>

#define D_DIM 128
#define NROW 8192
#define MROW 8192
#define TILE 128
#define LDK2 72      // shorts per LDS row for a K=64 chunk (64 data + 8 pad) = 144 B
#define OUT_LD 8192

typedef __bf16 bf16x8 __attribute__((ext_vector_type(8)));
typedef float f32x4 __attribute__((ext_vector_type(4)));

// Native RNE converts (v_cvt_pk_bf16_f32 on gfx950).
__device__ __forceinline__ ushort4 cvt4(float4 v) {
    union { __bf16 h[4]; ushort4 u; } r;
    r.h[0] = (__bf16)v.x; r.h[1] = (__bf16)v.y;
    r.h[2] = (__bf16)v.z; r.h[3] = (__bf16)v.w;
    return r.u;
}

// Exact f32 row norms: one wave per row, X rows then Y rows, into d_ws.
__global__ __launch_bounds__(256) void rbf_norms(const float* __restrict__ X,
                                                 const float* __restrict__ Y,
                                                 float* __restrict__ nrm) {
    const int t = threadIdx.x;
    const int w = t >> 6, lane = t & 63;
    const int rid = blockIdx.x * 4 + w;
    const float* src = (rid < NROW) ? (X + (size_t)rid * D_DIM)
                                    : (Y + (size_t)(rid - NROW) * D_DIM);
    float2 v = *(const float2*)(src + 2 * lane);
    float s = v.x * v.x + v.y * v.y;
    #pragma unroll
    for (int off = 32; off > 0; off >>= 1) s += __shfl_xor(s, off, 64);
    if (lane == 0) nrm[rid] = s;
}

// Round-2 LDS structure + XCD-aware swizzle for L2-resident inputs.
// MFMA operands swapped (A=Y frag, B=X frag) -> acc regs are 4 consecutive out
// columns for one out row -> direct dwordx4 NT stores.
__global__ __launch_bounds__(256, 4) void rbf_main(const float* __restrict__ X,
                                                   const float* __restrict__ Y,
                                                   const float* __restrict__ sigma,
                                                   const float* __restrict__ nrm,
                                                   float* __restrict__ out) {
    __shared__ unsigned short Xs[TILE][LDK2];   // 18432 B
    __shared__ unsigned short Ys[TILE][LDK2];   // 18432 B

    // XCD swizzle: b&7 = XCD (round-robin dispatch). Each XCD owns an
    // 8-block-row band (1024 X rows); iterates 8x8 block groups across the
    // 64 block-cols. Live inputs/XCD ~1.5 MB -> fits 4 MiB per-XCD L2.
    const int b = blockIdx.x;
    const int xcd = b & 7;
    const int s = b >> 3;                 // 0..511 within XCD
    const int grp = s >> 6;               // col-panel 0..7
    const int i = s & 63;
    const int row0 = (xcd * 8 + (i >> 3)) * TILE;   // X rows (out rows)
    const int col0 = (grp * 8 + (i & 7)) * TILE;    // Y rows (out cols)

    const int t = threadIdx.x;
    const int w = t >> 6, ln = t & 63;
    const int quad = ln >> 4, l16 = ln & 15;
    const int wr = (w >> 1) * 64;   // X-dim half of the tile for this wave
    const int wc = (w & 1) * 64;    // Y-dim half

    f32x4 acc[4][4] = {};   // [ti = out-row 16-frag][tj = out-col 16-frag]

    #pragma unroll
    for (int p = 0; p < 2; ++p) {
        // Stage 128 rows x 64 k of X and Y (f32 -> bf16 into LDS).
        #pragma unroll
        for (int it = 0; it < 8; ++it) {
            int f = t + 256 * it;
            int r = f >> 4;            // tile row 0..127
            int c = (f & 15) * 4;      // k offset within chunk, 0..60 step 4
            float4 vx = *(const float4*)(X + (size_t)(row0 + r) * D_DIM + p * 64 + c);
            float4 vy = *(const float4*)(Y + (size_t)(col0 + r) * D_DIM + p * 64 + c);
            *(ushort4*)(&Xs[r][c]) = cvt4(vx);
            *(ushort4*)(&Ys[r][c]) = cvt4(vy);
        }
        __syncthreads();

        #pragma unroll
        for (int ks = 0; ks < 2; ++ks) {
            const int k = ks * 32 + quad * 8;
            bf16x8 ax[4], by[4];
            #pragma unroll
            for (int ti = 0; ti < 4; ++ti)
                ax[ti] = *(const bf16x8*)(&Xs[wr + ti * 16 + l16][k]);
            #pragma unroll
            for (int tj = 0; tj < 4; ++tj)
                by[tj] = *(const bf16x8*)(&Ys[wc + tj * 16 + l16][k]);
            #pragma unroll
            for (int ti = 0; ti < 4; ++ti)
                #pragma unroll
                for (int tj = 0; tj < 4; ++tj)
                    acc[ti][tj] = __builtin_amdgcn_mfma_f32_16x16x32_bf16(by[tj], ax[ti], acc[ti][tj], 0, 0, 0);
        }
        if (p == 0) __syncthreads();   // phase-0 reads done before phase-1 restage
    }

    const float s2 = sigma[0] * sigma[0] + 1e-9f;
    const float cexp = -1.4426950408889634f / s2;   // exp(-d/s2) = exp2(d * cexp)

    // D layout: col(n)=l16 -> out row; row(m)=quad*4+r -> out col.
    // tj-inner so the two 64B halves of each 128B line are stored back-to-back.
    #pragma unroll
    for (int ti = 0; ti < 4; ++ti) {
        const float x2 = nrm[row0 + wr + ti * 16 + l16];
        const size_t grow = (size_t)(row0 + wr + ti * 16 + l16);
        #pragma unroll
        for (int tj = 0; tj < 4; ++tj) {
            f32x4 y2v = *(const f32x4*)(nrm + NROW + col0 + wc + tj * 16 + quad * 4);
            f32x4 v;
            #pragma unroll
            for (int r = 0; r < 4; ++r) {
                float d = x2 + y2v[r] - 2.0f * acc[ti][tj][r];
                v[r] = __builtin_amdgcn_exp2f(d * cexp);
            }
            size_t gcol = (size_t)(col0 + wc + tj * 16 + quad * 4);
            __builtin_nontemporal_store(v, (f32x4*)(out + grow * OUT_LD + gcol));
        }
    }
}

extern "C" void kernel_launch(void* const* d_in, const int* in_sizes, int n_in,
                              void* d_out, int out_size, void* d_ws, size_t ws_size,
                              hipStream_t stream) {
    const float* X = (const float*)d_in[0];
    const float* Y = (const float*)d_in[1];
    const float* sigma = (const float*)d_in[2];
    float* nrm = (float*)d_ws;          // 16384 f32 = 64 KB scratch
    float* out = (float*)d_out;

    rbf_norms<<<(NROW + MROW) / 4, 256, 0, stream>>>(X, Y, nrm);
    rbf_main<<<(NROW / TILE) * (MROW / TILE), 256, 0, stream>>>(X, Y, sigma, nrm, out);
}

// Round 5
// 314.079 us; speedup vs baseline: 1.2075x; 1.0024x over previous
//
#include <hip/hip_runtime.h>
#include <stdint.h>

#define D_DIM 128
#define NROW 8192
#define MROW 8192
#define OUT_LD 8192
#define LDP 136      // padded shorts per LDS row (272 B: rows advance 4 banks -> 2-way max, free)
#define BAND 16      // output rows per block
#define CTILE 128    // output cols per Y tile
#define NTILE (MROW / CTILE)

typedef __bf16 bf16x8 __attribute__((ext_vector_type(8)));
typedef float f32x4 __attribute__((ext_vector_type(4)));
typedef unsigned short us8 __attribute__((ext_vector_type(8)));

// Fused: bf16 conversion of X,Y into d_ws + exact f32 row norms.
__global__ __launch_bounds__(256) void rbf_prep(const float* __restrict__ X,
                                                const float* __restrict__ Y,
                                                float* __restrict__ nrm,
                                                unsigned short* __restrict__ Xb,
                                                unsigned short* __restrict__ Yb) {
    const int t = threadIdx.x;
    const int w = t >> 6, lane = t & 63;
    const int rid = blockIdx.x * 4 + w;
    const float* src;
    unsigned short* dst;
    if (rid < NROW) { src = X + (size_t)rid * D_DIM;          dst = Xb + (size_t)rid * D_DIM; }
    else            { src = Y + (size_t)(rid - NROW) * D_DIM; dst = Yb + (size_t)(rid - NROW) * D_DIM; }
    float2 v = *(const float2*)(src + 2 * lane);
    union { __bf16 h[2]; uint32_t u; } cv;
    cv.h[0] = (__bf16)v.x; cv.h[1] = (__bf16)v.y;          // RNE via v_cvt
    *(uint32_t*)(dst + 2 * lane) = cv.u;
    float s = v.x * v.x + v.y * v.y;
    #pragma unroll
    for (int off = 32; off > 0; off >>= 1) s += __shfl_xor(s, off, 64);
    if (lane == 0) nrm[rid] = s;
}

// Band-persistent: block owns out rows [row0, row0+16); X band in LDS once;
// sweeps all 64 Y-tiles (every block same order -> XCD-L2-shared Y stream).
// mfma(A=Yfrag, B=Xfrag): D col(n)=l16 -> out row, row(m)=quad*4+r -> out col,
// so each acc f32x4 = 4 consecutive out cols -> direct dwordx4 NT stores.
__global__ __launch_bounds__(256, 2) void rbf_band(const unsigned short* __restrict__ Xb,
                                                   const unsigned short* __restrict__ Yb,
                                                   const float* __restrict__ sigma,
                                                   const float* __restrict__ nrm,
                                                   float* __restrict__ out) {
    __shared__ __align__(16) unsigned short Ys[2][CTILE][LDP];  // 69632 B
    __shared__ __align__(16) unsigned short Xs[BAND][LDP];      //  4352 B

    const int t = threadIdx.x;
    const int w = t >> 6, ln = t & 63;
    const int quad = ln >> 4, l16 = ln & 15;
    const int row0 = blockIdx.x * BAND;
    const int yw = w * 32;                 // wave's 32-col slice of the tile

    // Stage X band (16 rows x 128 k bf16 = 4 KB), one 16 B chunk per thread.
    {
        int r = t >> 4, k = (t & 15) * 8;
        *(us8*)(&Xs[r][k]) = *(const us8*)(Xb + (size_t)(row0 + r) * D_DIM + k);
    }

    auto stageY = [&](int ct, int buf) {
        #pragma unroll
        for (int i = 0; i < 8; ++i) {
            int f = t + 256 * i;
            int r = f >> 4;           // 0..127
            int k = (f & 15) * 8;     // 0..120
            *(us8*)(&Ys[buf][r][k]) = *(const us8*)(Yb + (size_t)(ct * CTILE + r) * D_DIM + k);
        }
    };

    stageY(0, 0);
    __syncthreads();

    const float x2 = nrm[row0 + l16];
    const float s2 = sigma[0] * sigma[0] + 1e-9f;
    const float cexp = -1.4426950408889634f / s2;   // exp(-d/s2) = exp2(d*cexp)
    float* orow = out + (size_t)(row0 + l16) * OUT_LD;

    for (int ct = 0; ct < NTILE; ++ct) {
        const int cur = ct & 1;
        if (ct < NTILE - 1) stageY(ct + 1, cur ^ 1);

        f32x4 acc[2] = {};
        #pragma unroll
        for (int ks = 0; ks < 4; ++ks) {
            const int k = ks * 32 + quad * 8;
            bf16x8 b = *(const bf16x8*)(&Xs[l16][k]);
            #pragma unroll
            for (int tj = 0; tj < 2; ++tj) {
                bf16x8 a = *(const bf16x8*)(&Ys[cur][yw + tj * 16 + l16][k]);
                acc[tj] = __builtin_amdgcn_mfma_f32_16x16x32_bf16(a, b, acc[tj], 0, 0, 0);
            }
        }

        #pragma unroll
        for (int tj = 0; tj < 2; ++tj) {
            const int colb = ct * CTILE + yw + tj * 16 + quad * 4;
            f32x4 y2v = *(const f32x4*)(nrm + NROW + colb);
            f32x4 v;
            #pragma unroll
            for (int r = 0; r < 4; ++r) {
                float d = x2 + y2v[r] - 2.0f * acc[tj][r];
                v[r] = __builtin_amdgcn_exp2f(d * cexp);
            }
            __builtin_nontemporal_store(v, (f32x4*)(orow + colb));
        }
        __syncthreads();   // reads of cur done before it's restaged; writes of cur^1 visible
    }
}

extern "C" void kernel_launch(void* const* d_in, const int* in_sizes, int n_in,
                              void* d_out, int out_size, void* d_ws, size_t ws_size,
                              hipStream_t stream) {
    const float* X = (const float*)d_in[0];
    const float* Y = (const float*)d_in[1];
    const float* sigma = (const float*)d_in[2];
    float* nrm = (float*)d_ws;                                   // 16384 f32 = 64 KB
    unsigned short* Xb = (unsigned short*)d_ws + 32768;          // 2 MB bf16 X
    unsigned short* Yb = Xb + (size_t)NROW * D_DIM;              // 2 MB bf16 Y
    float* out = (float*)d_out;

    rbf_prep<<<(NROW + MROW) / 4, 256, 0, stream>>>(X, Y, nrm, Xb, Yb);
    rbf_band<<<NROW / BAND, 256, 0, stream>>>(Xb, Yb, sigma, nrm, out);
}